// Round 6
// baseline (286.688 us; speedup 1.0000x reference)
//
#include <hip/hip_runtime.h>

#define Fdim 128
#define Bsz  8192
#define Pn   6
#define EPSI 1e-5f
#define X2P 130       // x2 pitch: 65-dword rows (odd) -> conflict-free 32-row b128 reads
#define X1P 66        // x1 pitch: 33-dword rows (odd) -> conflict-free 32-row b128 reads

typedef _Float16 half8   __attribute__((ext_vector_type(8)));
typedef _Float16 half4t  __attribute__((ext_vector_type(4)));
typedef float    float4t __attribute__((ext_vector_type(4)));
typedef float    float16t __attribute__((ext_vector_type(16)));
typedef unsigned uint4v  __attribute__((ext_vector_type(4)));

__constant__ int PAIR_A[6] = {0,0,0,1,1,2};
__constant__ int PAIR_B[6] = {1,2,3,2,3,3};

// ---------------------------------------------------------------------------
// A-fragment build: a = v * broadcast(one half of dword s). Exactly 4
// v_pk_mul_f16 with op_sel folding the broadcast (no extract/splat glue).
// R5 post-mortem: compiler's splat codegen cost ~117 VALU cyc/ii vs 32 ideal.
// ---------------------------------------------------------------------------
__device__ __forceinline__ half8 bmul_lo(half8 v, unsigned s) {
    uint4v x = __builtin_bit_cast(uint4v, v);
    unsigned r0, r1, r2, r3;
    asm("v_pk_mul_f16 %0, %1, %2 op_sel:[0,0] op_sel_hi:[1,0]" : "=v"(r0) : "v"(x[0]), "v"(s));
    asm("v_pk_mul_f16 %0, %1, %2 op_sel:[0,0] op_sel_hi:[1,0]" : "=v"(r1) : "v"(x[1]), "v"(s));
    asm("v_pk_mul_f16 %0, %1, %2 op_sel:[0,0] op_sel_hi:[1,0]" : "=v"(r2) : "v"(x[2]), "v"(s));
    asm("v_pk_mul_f16 %0, %1, %2 op_sel:[0,0] op_sel_hi:[1,0]" : "=v"(r3) : "v"(x[3]), "v"(s));
    uint4v o = {r0, r1, r2, r3};
    return __builtin_bit_cast(half8, o);
}
__device__ __forceinline__ half8 bmul_hi(half8 v, unsigned s) {
    uint4v x = __builtin_bit_cast(uint4v, v);
    unsigned r0, r1, r2, r3;
    asm("v_pk_mul_f16 %0, %1, %2 op_sel:[0,1] op_sel_hi:[1,1]" : "=v"(r0) : "v"(x[0]), "v"(s));
    asm("v_pk_mul_f16 %0, %1, %2 op_sel:[0,1] op_sel_hi:[1,1]" : "=v"(r1) : "v"(x[1]), "v"(s));
    asm("v_pk_mul_f16 %0, %1, %2 op_sel:[0,1] op_sel_hi:[1,1]" : "=v"(r2) : "v"(x[2]), "v"(s));
    asm("v_pk_mul_f16 %0, %1, %2 op_sel:[0,1] op_sel_hi:[1,1]" : "=v"(r3) : "v"(x[3]), "v"(s));
    uint4v o = {r0, r1, r2, r3};
    return __builtin_bit_cast(half8, o);
}

// ---------------------------------------------------------------------------
// Kernel 1: W [128 x 16384] fp32 -> f16 32x32x16 B-fragments (layout as R5)
// + zeroes ssum/ssq (block 0) so the separate memset dispatch is dropped.
// Frag f = ntile*1024 + jc16*128 + i; element (f*64+lane)*8+e holds
// W[n = ntile*32 + (lane&31)][k = i*128 + jc16*16 + (lane>>5)*8 + e].
// ---------------------------------------------------------------------------
__global__ __launch_bounds__(256) void wprep(const float* __restrict__ W,
                                             _Float16* __restrict__ Wws,
                                             float* __restrict__ stats) {
    if (blockIdx.x == 0) {
        for (int i = threadIdx.x; i < 2 * Pn * Fdim; i += 256) stats[i] = 0.f;
    }
    int t    = blockIdx.x * 256 + threadIdx.x;  // 0..262143 = 4096 frags * 64 lanes
    int f    = t >> 6;
    int lane = t & 63;
    int ntile = f >> 10;
    int jc    = (f >> 7) & 7;
    int i     = f & 127;
    int q1 = lane >> 5;
    int nn = lane & 31;
    int n  = ntile * 32 + nn;
    int k0 = i * 128 + jc * 16 + q1 * 8;
    const float4t* src = (const float4t*)(W + (size_t)n * 16384 + k0);
    float4t a0 = src[0];
    float4t a1 = src[1];
    half8 h;
    h[0] = (_Float16)a0[0]; h[1] = (_Float16)a0[1];
    h[2] = (_Float16)a0[2]; h[3] = (_Float16)a0[3];
    h[4] = (_Float16)a1[0]; h[5] = (_Float16)a1[1];
    h[6] = (_Float16)a1[2]; h[7] = (_Float16)a1[3];
    *(half8*)(Wws + (size_t)t * 8) = h;
}

// ---------------------------------------------------------------------------
// Kernel 2: 32x32x16, wave = 64 rows x 64 cols (mt=2 x nt=2) + split-K.
// R5 post-mortem: MfmaUtil(56)+VALUBusy(39) = 95% -> pipes serialize, so
// minimize VALU absolutely. nt=2 amortizes each A-build over 2 MFMAs (8 pk
// per 4 MFMA, was 16) and op_sel asm kills the splat glue. W addressing via
// uniform SGPR stream pointers (readfirstlane'd wave id) bumped +=64/ii ->
// saddr + imm, SALU only. Wave grid 2x2 = (wrow: 64-row half) x (kw: jc
// split). Partials combined via LDS (x2t region, dead post-loop); kw=0
// waves do the epilogue. Grid 768 = 3 blocks/CU, one round. W stream
// prefetch (dist 4 per stream) overshoots <=4 KB past its chunk; global
// tail lands in yws (Wws FIRST in ws, values discarded).
// ---------------------------------------------------------------------------
__global__ __launch_bounds__(256, 3) void gemm(const float* __restrict__ x,
                                               const _Float16* __restrict__ Wws,
                                               _Float16* __restrict__ yws,
                                               float* __restrict__ ssum,
                                               float* __restrict__ ssq) {
    __shared__ __align__(16) _Float16 x2t[128 * X2P];    // 33280 B: 128 rows x 128 j
    __shared__ __align__(16) _Float16 x1th[128 * X1P];   // 16896 B: 128 rows x 64 i

    int bid  = blockIdx.x;
    int p    = bid >> 7;
    int rem  = bid & 127;
    int mblk = rem >> 1;          // 64 m-blocks of 128 rows
    int nh   = rem & 1;
    int m0   = mblk * 128;
    int v1   = PAIR_A[p];
    int v2   = PAIR_B[p];
    int tid  = threadIdx.x;

    // ---- stage x2 tile (full 128x128, fp32 -> f16) ------------------------
    {
        const float4t* s2p = (const float4t*)(x + ((size_t)v2 * Bsz + m0) * Fdim);
        for (int it = 0; it < 16; ++it) {
            int idx = it * 256 + tid;
            int row = idx >> 5;
            int col = (idx & 31) * 4;
            float4t b = s2p[idx];
            half4t h2; h2[0]=(_Float16)b[0]; h2[1]=(_Float16)b[1];
                       h2[2]=(_Float16)b[2]; h2[3]=(_Float16)b[3];
            *(half4t*)&x2t[row * X2P + col] = h2;
        }
    }

    int lane = tid & 63;
    int w    = __builtin_amdgcn_readfirstlane(tid >> 6);  // force SGPR wave id
    int wrow = w & 1;             // 64-row half
    int kw   = w >> 1;            // split-K: jc in {kw*4 .. kw*4+3}
    int nn   = lane & 31;
    int q1   = lane >> 5;

    float16t acc[2][2];
#pragma unroll
    for (int mt = 0; mt < 2; ++mt)
#pragma unroll
        for (int nt = 0; nt < 2; ++nt)
#pragma unroll
            for (int e = 0; e < 16; ++e)
                acc[mt][nt][e] = 0.f;

    const half8* wb = (const half8*)Wws;
    const float* x1src = x + ((size_t)v1 * Bsz + m0) * Fdim;

    // hoisted per-lane LDS base pointers (rows fixed per wave/mt)
    const _Float16* x2p0 = &x2t[(wrow * 64 + nn) * X2P + q1 * 8];
    const _Float16* x2p1 = &x2t[(wrow * 64 + 32 + nn) * X2P + q1 * 8];
    const _Float16* x1p0 = &x1th[(wrow * 64 + nn) * X1P];
    const _Float16* x1p1 = &x1th[(wrow * 64 + 32 + nn) * X1P];

    for (int kh = 0; kh < 2; ++kh) {
        if (kh) __syncthreads();      // all reads of previous x1 half done
        // ---- stage x1 half-tile: 128 rows x 64 i-cols ---------------------
        for (int it = 0; it < 8; ++it) {
            int idx = it * 256 + tid;
            int row = idx >> 4;
            int c4  = (idx & 15) * 4;
            float4t a = *(const float4t*)(x1src + (size_t)row * Fdim + kh * 64 + c4);
            half4t h1; h1[0]=(_Float16)a[0]; h1[1]=(_Float16)a[1];
                       h1[2]=(_Float16)a[2]; h1[3]=(_Float16)a[3];
            *(half4t*)&x1th[row * X1P + c4] = h1;
        }
        __syncthreads();

#pragma unroll 1
        for (int jcl = 0; jcl < 4; ++jcl) {
            int jc = kw * 4 + jcl;    // this wave's 16-j chunk
            // x2 fragments: constant across the whole i-sweep of this jc
            half8 x2f0 = *(const half8*)(x2p0 + jc * 16);
            half8 x2f1 = *(const half8*)(x2p1 + jc * 16);

            // two W streams (nt=0,1), uniform SGPR pointers, dist-4 rings
            const half8* wpA = wb + (size_t)(((nh * 2 + 0) * 1024 + jc * 128 + kh * 64) * 64);
            const half8* wpB = wb + (size_t)(((nh * 2 + 1) * 1024 + jc * 128 + kh * 64) * 64);
            half8 wbufA[4], wbufB[4];
#pragma unroll
            for (int d = 0; d < 4; ++d) {
                wbufA[d] = wpA[lane + d * 64];
                wbufB[d] = wpB[lane + d * 64];
            }

#pragma unroll
            for (int il8 = 0; il8 < 8; ++il8) {
                half8 x1f0 = *(const half8*)(x1p0 + il8 * 8);
                half8 x1f1 = *(const half8*)(x1p1 + il8 * 8);
                uint4v s0v = __builtin_bit_cast(uint4v, x1f0);
                uint4v s1v = __builtin_bit_cast(uint4v, x1f1);
#pragma unroll
                for (int ii = 0; ii < 8; ++ii) {
                    const int sl = ii & 3;          // ring slot (il8*8 = 0 mod 4)
                    unsigned sd0 = s0v[ii >> 1];
                    unsigned sd1 = s1v[ii >> 1];
                    half8 a0, a1;
                    if ((ii & 1) == 0) { a0 = bmul_lo(x2f0, sd0); a1 = bmul_lo(x2f1, sd1); }
                    else               { a0 = bmul_hi(x2f0, sd0); a1 = bmul_hi(x2f1, sd1); }
                    acc[0][0] = __builtin_amdgcn_mfma_f32_32x32x16_f16(a0, wbufA[sl], acc[0][0], 0, 0, 0);
                    acc[0][1] = __builtin_amdgcn_mfma_f32_32x32x16_f16(a0, wbufB[sl], acc[0][1], 0, 0, 0);
                    acc[1][0] = __builtin_amdgcn_mfma_f32_32x32x16_f16(a1, wbufA[sl], acc[1][0], 0, 0, 0);
                    acc[1][1] = __builtin_amdgcn_mfma_f32_32x32x16_f16(a1, wbufB[sl], acc[1][1], 0, 0, 0);
                    // dist-4 prefetch: frag il+4 at imm offset 256*16B = 4096
                    wbufA[sl] = wpA[lane + 256];
                    wbufB[sl] = wpB[lane + 256];
                    wpA += 64; wpB += 64;          // uniform SALU bump
                }
                __builtin_amdgcn_sched_barrier(0);  // bound hoist window
            }
        }
    }

    // ---- split-K combine (via x2t region, dead now) -----------------------
    __syncthreads();                  // everyone done reading x2t / x1th
    float4t* xch = (float4t*)x2t;     // 2 kw=1 waves x 16 KB = 32 KB <= 33280 B
    if (kw == 1) {
#pragma unroll
        for (int mt = 0; mt < 2; ++mt)
#pragma unroll
            for (int nt = 0; nt < 2; ++nt)
#pragma unroll
                for (int r4 = 0; r4 < 4; ++r4) {
                    float4t v = {acc[mt][nt][r4*4+0], acc[mt][nt][r4*4+1],
                                 acc[mt][nt][r4*4+2], acc[mt][nt][r4*4+3]};
                    xch[((wrow * 4 + mt * 2 + nt) * 4 + r4) * 64 + lane] = v;
                }
    }
    __syncthreads();
    if (kw == 0) {
#pragma unroll
        for (int mt = 0; mt < 2; ++mt)
#pragma unroll
            for (int nt = 0; nt < 2; ++nt)
#pragma unroll
                for (int r4 = 0; r4 < 4; ++r4) {
                    float4t v = xch[((wrow * 4 + mt * 2 + nt) * 4 + r4) * 64 + lane];
                    acc[mt][nt][r4*4+0] += v[0]; acc[mt][nt][r4*4+1] += v[1];
                    acc[mt][nt][r4*4+2] += v[2]; acc[mt][nt][r4*4+3] += v[3];
                }

        // ---- epilogue: store y (f16) + per-o stats ------------------------
        // C/D 32x32 layout: col = lane&31, row = (r&3) + 8*(r>>2) + 4*q1.
        float sum[2] = {0.f, 0.f};
        float sq[2]  = {0.f, 0.f};
#pragma unroll
        for (int mt = 0; mt < 2; ++mt) {
#pragma unroll
            for (int nt = 0; nt < 2; ++nt) {
                int colg = (nh * 2 + nt) * 32 + nn;
#pragma unroll
                for (int r = 0; r < 16; ++r) {
                    int rl = (r & 3) + 8 * (r >> 2) + 4 * q1;
                    size_t row = (size_t)p * Bsz + m0 + wrow * 64 + mt * 32 + rl;
                    float v = acc[mt][nt][r];
                    sum[nt] += v; sq[nt] += v * v;
                    yws[row * Fdim + colg] = (_Float16)v;
                }
            }
        }
#pragma unroll
        for (int nt = 0; nt < 2; ++nt) {
            sum[nt] += __shfl_xor(sum[nt], 32, 64);
            sq[nt]  += __shfl_xor(sq[nt], 32, 64);
        }
        if (q1 == 0) {
#pragma unroll
            for (int nt = 0; nt < 2; ++nt) {
                int colg = (nh * 2 + nt) * 32 + nn;
                atomicAdd(&ssum[p * Fdim + colg], sum[nt]);
                atomicAdd(&ssq [p * Fdim + colg], sq[nt]);
            }
        }
    }
}

// ---------------------------------------------------------------------------
// Kernel 3: BN (train-mode batch stats, biased var) + ReLU, f16 y -> fp32 out.
// ---------------------------------------------------------------------------
__global__ __launch_bounds__(256) void bnrelu(const _Float16* __restrict__ yws,
                                              const float* __restrict__ ssum,
                                              const float* __restrict__ ssq,
                                              const float* __restrict__ gamma,
                                              const float* __restrict__ beta,
                                              float* __restrict__ out) {
    __shared__ float gs[128], sh[128];
    size_t ebase = (size_t)blockIdx.x * 1024;
    int p = (int)(ebase >> 20);            // B*F = 2^20
    int t = threadIdx.x;
    if (t < 128) {
        float mean = ssum[p * Fdim + t] * (1.0f / 8192.0f);
        float var  = ssq [p * Fdim + t] * (1.0f / 8192.0f) - mean * mean;
        float g    = gamma[t] * rsqrtf(var + EPSI);
        gs[t] = g;
        sh[t] = beta[t] - g * mean;
    }
    __syncthreads();
    size_t e0 = ebase + (size_t)t * 4;
    int o0 = (int)(e0 & 127);
    half4t y = *(const half4t*)(yws + e0);
    float4t r;
#pragma unroll
    for (int l = 0; l < 4; ++l) {
        float v = fmaf(gs[o0 + l], (float)y[l], sh[o0 + l]);
        r[l] = v > 0.f ? v : 0.f;
    }
    *(float4t*)(out + e0) = r;
}

// ---------------------------------------------------------------------------
extern "C" void kernel_launch(void* const* d_in, const int* in_sizes, int n_in,
                              void* d_out, int out_size, void* d_ws, size_t ws_size,
                              hipStream_t stream) {
    const float* x     = (const float*)d_in[0];
    const float* W     = (const float*)d_in[1];
    // d_in[2] = linear bias b: mathematically cancelled by train-mode BN.
    const float* gamma = (const float*)d_in[3];
    const float* beta  = (const float*)d_in[4];
    float* out = (float*)d_out;

    // Layout: Wws FIRST so the W-stream's <=4 KB K-tail overshoot lands in
    // yws (allocated, values discarded) instead of past the workspace.
    char* ws = (char*)d_ws;
    _Float16* Wws = (_Float16*)ws;                       // 128*16384*2  =  4,194,304 B
    _Float16* yws = (_Float16*)(ws + 4194304);           // 6*8192*128*2 = 12,582,912 B
    float*    ssum = (float*)(ws + 16777216);            // 768 floats
    float*    ssq  = ssum + Pn * Fdim;                   // 768 floats (contiguous)

    wprep<<<1024, 256, 0, stream>>>(W, Wws, ssum);       // also zeroes ssum/ssq
    gemm<<<768, 256, 0, stream>>>(x, Wws, yws, ssum, ssq);
    bnrelu<<<6144, 256, 0, stream>>>(yws, ssum, ssq, gamma, beta, out);
}